// Round 1
// baseline (1196.813 us; speedup 1.0000x reference)
//
#include <hip/hip_runtime.h>
#include <stdint.h>

#define V_SZ   1000000
#define N0_SZ  1048576
#define N1_SZ  131072
#define N2_SZ  16384
#define E0_SZ  1048576
#define E1_SZ  131072
#define EP_SZ  16384

typedef short bf16x8 __attribute__((ext_vector_type(8)));
typedef float f32x4  __attribute__((ext_vector_type(4)));

__device__ __forceinline__ unsigned short f2bf(float f) {
  union { float f; unsigned u; } v; v.f = f;
  unsigned r = v.u + 0x7FFFu + ((v.u >> 16) & 1u);   // RNE
  return (unsigned short)(r >> 16);
}
__device__ __forceinline__ float bf2f(unsigned short h) {
  union { unsigned u; float f; } v; v.u = ((unsigned)h) << 16;
  return v.f;
}
__device__ __forceinline__ unsigned pack2bf(float a, float b) {
  return ((unsigned)f2bf(b) << 16) | (unsigned)f2bf(a);
}

// ---------- merged weight prep: 4 weights f32 (K x 128) -> bf16 (128 x K) ----------
__global__ __launch_bounds__(256) void prepw_all_k(
    const float* __restrict__ Q0w, const float* __restrict__ W0w,
    const float* __restrict__ Q1w, const float* __restrict__ W1w,
    unsigned short* __restrict__ Q0T, unsigned short* __restrict__ W0T,
    unsigned short* __restrict__ Q1T, unsigned short* __restrict__ W1T) {
  int t = blockIdx.x * 256 + threadIdx.x;   // total 98304
  const float* W; unsigned short* WT; int K; int base;
  if (t < 16384)      { W = Q0w; WT = Q0T; K = 128; base = 0; }
  else if (t < 49152) { W = W0w; WT = W0T; K = 256; base = 16384; }
  else if (t < 65536) { W = Q1w; WT = Q1T; K = 128; base = 49152; }
  else                { W = W1w; WT = W1T; K = 256; base = 65536; }
  int u = t - base;
  int n = u & 127, k = u >> 7;
  WT[(size_t)n * K + k] = f2bf(W[u]);
}

// ---------- merged CSR build (both layers; counts0|counts1 contiguous) ----------
__global__ __launch_bounds__(256) void hist_all_k(const int* __restrict__ dst0,
                                                  const int* __restrict__ dst1,
                                                  int* __restrict__ counts) {
  int e = blockIdx.x * 256 + threadIdx.x;   // E0+E1
  if (e < E0_SZ) atomicAdd(&counts[dst0[e]], 1);
  else if (e < E0_SZ + E1_SZ) atomicAdd(&counts[N1_SZ + dst1[e - E0_SZ]], 1);
}

// per-1024-chunk sums over the combined counts array (144 blocks)
__global__ __launch_bounds__(256) void scan_bsums_k(const int* __restrict__ counts,
                                                    int* __restrict__ bsums) {
  __shared__ int red[256];
  int base = blockIdx.x * 1024, t = threadIdx.x;
  int s = 0;
  #pragma unroll
  for (int i = 0; i < 4; i++) s += counts[base + t * 4 + i];
  red[t] = s;
  __syncthreads();
  for (int st = 128; st > 0; st >>= 1) {
    if (t < st) red[t] += red[t + st];
    __syncthreads();
  }
  if (t == 0) bsums[blockIdx.x] = red[0];
}

// block 0: exclusive-scan bsums[0:128] (layer0); block 1: bsums[128:144] (layer1)
__global__ __launch_bounds__(256) void scan_top2_k(int* __restrict__ bsums,
                                                   int* __restrict__ offs0_last,
                                                   int* __restrict__ offs1_last) {
  __shared__ int lds[256];
  int b = blockIdx.x, t = threadIdx.x;
  int nb = (b == 0) ? 128 : 16;
  int off = (b == 0) ? 0 : 128;
  int v = (t < nb) ? bsums[off + t] : 0;
  lds[t] = v;
  __syncthreads();
  for (int st = 1; st < 256; st <<= 1) {
    int x = (t >= st) ? lds[t - st] : 0;
    __syncthreads();
    lds[t] += x;
    __syncthreads();
  }
  if (t < nb) bsums[off + t] = lds[t] - v;
  if (t == nb - 1) *((b == 0) ? offs0_last : offs1_last) = lds[t];
}

// final: exclusive scan within each 1024 chunk + add per-layer block prefix
__global__ __launch_bounds__(256) void scan_final_k(const int* __restrict__ counts,
                                                    const int* __restrict__ bsums,
                                                    int* __restrict__ offs0,
                                                    int* __restrict__ offs1) {
  __shared__ int tsum[256];
  int b = blockIdx.x, t = threadIdx.x;
  int base = b * 1024;
  int v0 = counts[base + t * 4 + 0], v1 = counts[base + t * 4 + 1];
  int v2 = counts[base + t * 4 + 2], v3 = counts[base + t * 4 + 3];
  int s = v0 + v1 + v2 + v3;
  tsum[t] = s;
  __syncthreads();
  for (int st = 1; st < 256; st <<= 1) {
    int x = (t >= st) ? tsum[t - st] : 0;
    __syncthreads();
    tsum[t] += x;
    __syncthreads();
  }
  int pre = bsums[b] + tsum[t] - s;
  int* op = (b < 128) ? (offs0 + base) : (offs1 + base - N1_SZ);
  op[t * 4 + 0] = pre;
  op[t * 4 + 1] = pre + v0;
  op[t * 4 + 2] = pre + v0 + v1;
  op[t * 4 + 3] = pre + v0 + v1 + v2;
}

// scatter edges into CSR slots; (src, w) packed into one 8B write
__global__ __launch_bounds__(256) void scatter_all_k(
    const int* __restrict__ src0, const int* __restrict__ dst0, const float* __restrict__ w0,
    const int* __restrict__ src1, const int* __restrict__ dst1, const float* __restrict__ w1,
    const int* __restrict__ offs0, const int* __restrict__ offs1,
    int* __restrict__ cursor,                      // cursor0(N1) | cursor1(N2)
    int2* __restrict__ esw0, int2* __restrict__ esw1) {
  int e = blockIdx.x * 256 + threadIdx.x;
  if (e < E0_SZ) {
    int d = dst0[e];
    int p = offs0[d] + atomicAdd(&cursor[d], 1);
    esw0[p] = make_int2(src0[e], __float_as_int(w0[e]));
  } else if (e < E0_SZ + E1_SZ) {
    int ee = e - E0_SZ;
    int d = dst1[ee];
    int p = offs1[d] + atomicAdd(&cursor[N1_SZ + d], 1);
    esw1[p] = make_int2(src1[ee], __float_as_int(w1[ee]));
  }
}

// ---------- fused gather-GEMM (rows x 128, K = 128*KCHUNKS) ----------
#define AM_GATHER 0
#define AM_BF16   1
#define EPI_BF16        0
#define EPI_NORM        1
#define EPI_NORM_ADDEMB 2

template <int KCHUNKS, int AM0, int AM1, int EPI>
__global__ __launch_bounds__(256) void gemm_k(const void* __restrict__ asrc0,
                                              const void* __restrict__ asrc1,
                                              const int* __restrict__ ids,
                                              const unsigned short* __restrict__ BT,
                                              const float* __restrict__ biasv,
                                              void* __restrict__ outp,
                                              const float* __restrict__ emb) {
  __shared__ unsigned short lA[64][136];
  __shared__ unsigned short lB[128][136];
  const int tid = threadIdx.x;
  const int lane = tid & 63;
  const int wid = tid >> 6;
  const int rowbase = blockIdx.x * 64;
  const int Ktot = KCHUNKS * 128;

  f32x4 acc[8];
  #pragma unroll
  for (int i = 0; i < 8; i++) acc[i] = (f32x4){0.f, 0.f, 0.f, 0.f};

  for (int c = 0; c < KCHUNKS; ++c) {
    if (c) __syncthreads();
    const int am = (c == 0) ? AM0 : AM1;
    const void* asrc = (c == 0) ? asrc0 : asrc1;
    if (am == AM_GATHER) {
      const float* fsrc = (const float*)asrc;
      #pragma unroll
      for (int i = 0; i < 8; i++) {
        int f = i * 256 + tid;
        int r = f >> 5, c4 = f & 31;
        const float* rp = fsrc + (size_t)ids[rowbase + r] * 128;
        float4 v = *(const float4*)(rp + c4 * 4);
        uint2 pk;
        pk.x = pack2bf(v.x, v.y);
        pk.y = pack2bf(v.z, v.w);
        *(uint2*)(&lA[r][c4 * 4]) = pk;
      }
    } else {
      const unsigned short* bsrc = (const unsigned short*)asrc;
      #pragma unroll
      for (int i = 0; i < 4; i++) {
        int f = i * 256 + tid;
        int r = f >> 4, c8 = f & 15;
        uint4 v = *(const uint4*)(bsrc + (size_t)(rowbase + r) * 128 + c8 * 8);
        *(uint4*)(&lA[r][c8 * 8]) = v;
      }
    }
    {
      const unsigned short* bp = BT + c * 128;
      #pragma unroll
      for (int i = 0; i < 8; i++) {
        int f = i * 256 + tid;
        int n = f >> 4, c8 = f & 15;
        uint4 v = *(const uint4*)(bp + (size_t)n * Ktot + c8 * 8);
        *(uint4*)(&lB[n][c8 * 8]) = v;
      }
    }
    __syncthreads();

    const int mr = wid * 16 + (lane & 15);
    const int kq = (lane >> 4) * 8;
    #pragma unroll
    for (int kk = 0; kk < 128; kk += 32) {
      bf16x8 af = *(const bf16x8*)(&lA[mr][kk + kq]);
      #pragma unroll
      for (int nt = 0; nt < 8; ++nt) {
        bf16x8 bfr = *(const bf16x8*)(&lB[nt * 16 + (lane & 15)][kk + kq]);
        acc[nt] = __builtin_amdgcn_mfma_f32_16x16x32_bf16(af, bfr, acc[nt], 0, 0, 0);
      }
    }
  }

  // epilogue: C/D layout col=lane&15 (+16*nt), row=(lane>>4)*4+r
  const int crow = wid * 16 + ((lane >> 4) << 2);
  float vreg[8][4];
  #pragma unroll
  for (int nt = 0; nt < 8; ++nt) {
    int col = nt * 16 + (lane & 15);
    float b = biasv[col];
    #pragma unroll
    for (int r = 0; r < 4; ++r) {
      float v = acc[nt][r] + b;
      vreg[nt][r] = v > 0.f ? v : 0.f;
    }
  }
  if (EPI == EPI_BF16) {
    unsigned short* op = (unsigned short*)outp;
    #pragma unroll
    for (int nt = 0; nt < 8; ++nt) {
      int col = nt * 16 + (lane & 15);
      #pragma unroll
      for (int r = 0; r < 4; ++r)
        op[(size_t)(rowbase + crow + r) * 128 + col] = f2bf(vreg[nt][r]);
    }
  } else {
    float ss[4] = {0.f, 0.f, 0.f, 0.f};
    #pragma unroll
    for (int nt = 0; nt < 8; ++nt)
      #pragma unroll
      for (int r = 0; r < 4; ++r) ss[r] += vreg[nt][r] * vreg[nt][r];
    #pragma unroll
    for (int r = 0; r < 4; ++r) {
      ss[r] += __shfl_xor(ss[r], 1);
      ss[r] += __shfl_xor(ss[r], 2);
      ss[r] += __shfl_xor(ss[r], 4);
      ss[r] += __shfl_xor(ss[r], 8);
    }
    float sc[4];
    #pragma unroll
    for (int r = 0; r < 4; ++r) sc[r] = ss[r] > 0.f ? rsqrtf(ss[r]) : 1.0f;
    if (EPI == EPI_NORM) {
      unsigned short* op = (unsigned short*)outp;
      #pragma unroll
      for (int nt = 0; nt < 8; ++nt) {
        int col = nt * 16 + (lane & 15);
        #pragma unroll
        for (int r = 0; r < 4; ++r)
          op[(size_t)(rowbase + crow + r) * 128 + col] = f2bf(vreg[nt][r] * sc[r]);
      }
    } else {
      float* op = (float*)outp;
      #pragma unroll
      for (int nt = 0; nt < 8; ++nt) {
        int col = nt * 16 + (lane & 15);
        #pragma unroll
        for (int r = 0; r < 4; ++r) {
          int row = rowbase + crow + r;
          op[(size_t)row * 128 + col] =
              vreg[nt][r] * sc[r] + emb[(size_t)ids[row] * 128 + col];
        }
      }
    }
  }
}

// ---------- fused per-edge Q-GEMM + weighted segment aggregation ----------
// Each block owns 64 CSR-consecutive dsts. Per 64-edge chunk:
//   stage gathered A rows -> MFMA with LDS-resident B (loaded once) ->
//   relu(+bias) written back into lA (own rows only) ->
//   segment-reduce into register accumulators (wave owns 16 dsts, lane owns 2 cols).
// Replaces {node-GEMM -> n write -> n gather-agg} with a single pass; the
// per-node and per-edge GEMM volumes are identical here (E == N per layer).
template <int LAYER>   // 0: A row = emb[nids[src]] (f32); 1: A row = hsrc[src] (bf16)
__global__ __launch_bounds__(256) void qagg_k(
    const float* __restrict__ embf,
    const unsigned short* __restrict__ hsrc,
    const int* __restrict__ nids,
    const int* __restrict__ offs,          // [ndst+1] CSR offsets
    const int2* __restrict__ esw,          // packed (src, w) per CSR slot
    const unsigned short* __restrict__ BT, // 128 x 128 bf16, n-major
    const float* __restrict__ biasv,
    unsigned short* __restrict__ aout) {
  __shared__ unsigned short lA[64][136];
  __shared__ unsigned short lB[128][136];
  __shared__ float lw[64];
  __shared__ int loffs[65];
  const int tid = threadIdx.x;
  const int lane = tid & 63;
  const int wid = tid >> 6;
  const int d0 = blockIdx.x * 64;

  // stage B once per block
  #pragma unroll
  for (int i = 0; i < 8; i++) {
    int f = i * 256 + tid;
    int n = f >> 4, c8 = f & 15;
    uint4 v = *(const uint4*)(BT + (size_t)n * 128 + c8 * 8);
    *(uint4*)(&lB[n][c8 * 8]) = v;
  }
  if (tid < 65) loffs[tid] = offs[d0 + tid];
  const int ebeg = offs[d0];        // uniform scalar loads (avoid loffs race)
  const int eend = offs[d0 + 64];

  const int mr = wid * 16 + (lane & 15);
  const int kq = (lane >> 4) * 8;
  const int crow = wid * 16 + ((lane >> 4) << 2);

  float bv[8];
  #pragma unroll
  for (int nt = 0; nt < 8; ++nt) bv[nt] = biasv[nt * 16 + (lane & 15)];

  float accD[16][2];
  float wsum[16];
  #pragma unroll
  for (int i = 0; i < 16; ++i) { accD[i][0] = 0.f; accD[i][1] = 0.f; wsum[i] = 0.f; }

  for (int base = ebeg; base < eend; base += 64) {
    const int nslots = min(64, eend - base);
    // ---- stage weights + gathered A rows ----
    if (tid < 64) lw[tid] = (tid < nslots) ? __int_as_float(esw[base + tid].y) : 0.f;
    if (LAYER == 0) {
      #pragma unroll
      for (int i = 0; i < 8; i++) {
        int f = i * 256 + tid;
        int r = f >> 5, c4 = f & 31;
        if (r < nslots) {
          int s = esw[base + r].x;
          const float* rp = embf + (size_t)nids[s] * 128;
          float4 v = *(const float4*)(rp + c4 * 4);
          uint2 pk;
          pk.x = pack2bf(v.x, v.y);
          pk.y = pack2bf(v.z, v.w);
          *(uint2*)(&lA[r][c4 * 4]) = pk;
        }
      }
    } else {
      #pragma unroll
      for (int i = 0; i < 4; i++) {
        int f = i * 256 + tid;
        int r = f >> 4, c8 = f & 15;
        if (r < nslots) {
          int s = esw[base + r].x;
          uint4 v = *(const uint4*)(hsrc + (size_t)s * 128 + c8 * 8);
          *(uint4*)(&lA[r][c8 * 8]) = v;
        }
      }
    }
    __syncthreads();   // (1) staging visible

    // ---- Q-GEMM on this chunk ----
    f32x4 acc[8];
    #pragma unroll
    for (int i = 0; i < 8; i++) acc[i] = (f32x4){0.f, 0.f, 0.f, 0.f};
    #pragma unroll
    for (int kk = 0; kk < 128; kk += 32) {
      bf16x8 af = *(const bf16x8*)(&lA[mr][kk + kq]);
      #pragma unroll
      for (int nt = 0; nt < 8; ++nt) {
        bf16x8 bfr = *(const bf16x8*)(&lB[nt * 16 + (lane & 15)][kk + kq]);
        acc[nt] = __builtin_amdgcn_mfma_f32_16x16x32_bf16(af, bfr, acc[nt], 0, 0, 0);
      }
    }
    // relu(+bias) -> write back into lA (this wave's own 16 rows only; no
    // other wave reads rows outside its own slice for A-fragments)
    #pragma unroll
    for (int nt = 0; nt < 8; ++nt) {
      int col = nt * 16 + (lane & 15);
      #pragma unroll
      for (int r = 0; r < 4; ++r) {
        float v = acc[nt][r] + bv[nt];
        lA[crow + r][col] = f2bf(v > 0.f ? v : 0.f);
      }
    }
    __syncthreads();   // (2) relu'd rows visible to all waves

    // ---- segment-reduce: wave wid owns dsts [wid*16, wid*16+16) ----
    #pragma unroll
    for (int dd = 0; dd < 16; ++dd) {
      const int d = wid * 16 + dd;
      int rb = loffs[d] - base;     rb = rb > 0 ? rb : 0;
      int re = loffs[d + 1] - base; re = re < nslots ? re : nslots;
      for (int r = rb; r < re; ++r) {
        float w = lw[r];
        unsigned u = *(const unsigned*)(&lA[r][lane * 2]);
        accD[dd][0] += w * bf2f((unsigned short)(u & 0xffffu));
        accD[dd][1] += w * bf2f((unsigned short)(u >> 16));
        wsum[dd] += w;
      }
    }
    __syncthreads();   // (3) done reading lA/lw before next chunk overwrites
  }

  // epilogue: a[d] = acc / clip(wsum, 1)
  #pragma unroll
  for (int dd = 0; dd < 16; ++dd) {
    const int d = d0 + wid * 16 + dd;
    float inv = 1.0f / fmaxf(wsum[dd], 1.0f);
    unsigned o = pack2bf(accD[dd][0] * inv, accD[dd][1] * inv);
    *(unsigned*)(aout + (size_t)d * 128 + lane * 2) = o;
  }
}

// ---------- final scores (bias gathered inline through nids) ----------
__global__ __launch_bounds__(256) void score_k(const float* __restrict__ hitem,
                                               const float* __restrict__ bias,
                                               const int* __restrict__ nids,
                                               const int* __restrict__ ps,
                                               const int* __restrict__ pd,
                                               const int* __restrict__ ns,
                                               const int* __restrict__ nd,
                                               float* __restrict__ out) {
  int wid = threadIdx.x >> 6, lane = threadIdx.x & 63;
  int e = blockIdx.x * 4 + wid;
  if (e >= EP_SZ) return;
  int a = ps[e], b = pd[e], c = ns[e], d = nd[e];
  float2 va = ((const float2*)(hitem + (size_t)a * 128))[lane];
  float2 vb = ((const float2*)(hitem + (size_t)b * 128))[lane];
  float2 vc = ((const float2*)(hitem + (size_t)c * 128))[lane];
  float2 vd = ((const float2*)(hitem + (size_t)d * 128))[lane];
  float dp = va.x * vb.x + va.y * vb.y;
  float dn = vc.x * vd.x + vc.y * vd.y;
  #pragma unroll
  for (int m = 1; m < 64; m <<= 1) {
    dp += __shfl_xor(dp, m);
    dn += __shfl_xor(dn, m);
  }
  if (lane == 0) {
    float sp = dp + bias[nids[a]] + bias[nids[b]];
    float sn = dn + bias[nids[c]] + bias[nids[d]];
    out[e] = fmaxf(sn - sp + 1.0f, 0.0f);
  }
}

extern "C" void kernel_launch(void* const* d_in, const int* in_sizes, int n_in,
                              void* d_out, int out_size, void* d_ws, size_t ws_size,
                              hipStream_t stream) {
  const float* emb  = (const float*)d_in[0];
  const float* bias = (const float*)d_in[1];
  const int* nids   = (const int*)d_in[2];
  const int* src0   = (const int*)d_in[3];
  const int* dst0   = (const int*)d_in[4];
  const float* w0   = (const float*)d_in[5];
  const int* src1   = (const int*)d_in[6];
  const int* dst1   = (const int*)d_in[7];
  const float* w1   = (const float*)d_in[8];
  const int* pos_src = (const int*)d_in[9];
  const int* pos_dst = (const int*)d_in[10];
  const int* neg_src = (const int*)d_in[11];
  const int* neg_dst = (const int*)d_in[12];
  const float* Q0w = (const float*)d_in[13];
  const float* Q0b = (const float*)d_in[14];
  const float* W0w = (const float*)d_in[15];
  const float* W0b = (const float*)d_in[16];
  const float* Q1w = (const float*)d_in[17];
  const float* Q1b = (const float*)d_in[18];
  const float* W1w = (const float*)d_in[19];
  const float* W1b = (const float*)d_in[20];
  float* out = (float*)d_out;

  char* ws = (char*)d_ws;
  size_t p = 0;
  auto carve = [&](size_t sz) { void* r = ws + p; p = (p + sz + 255) & ~(size_t)255; return r; };

  unsigned short* a0    = (unsigned short*)carve((size_t)N1_SZ * 128 * 2);
  unsigned short* h1    = (unsigned short*)carve((size_t)N1_SZ * 128 * 2);
  unsigned short* a1    = (unsigned short*)carve((size_t)N2_SZ * 128 * 2);
  float*          hitem = (float*)carve((size_t)N2_SZ * 128 * 4);
  unsigned short* Q0T = (unsigned short*)carve(128 * 128 * 2);
  unsigned short* W0T = (unsigned short*)carve(256 * 128 * 2);
  unsigned short* Q1T = (unsigned short*)carve(128 * 128 * 2);
  unsigned short* W1T = (unsigned short*)carve(256 * 128 * 2);
  // counts0(N1)|counts1(N2)|cursor0(N1)|cursor1(N2) contiguous -> one memset
  int* cnt_all = (int*)carve((size_t)(N1_SZ + N2_SZ) * 2 * 4);
  int* counts  = cnt_all;
  int* cursor  = cnt_all + (N1_SZ + N2_SZ);
  int*  offs0 = (int*)carve((N1_SZ + 1) * 4);
  int*  offs1 = (int*)carve((N2_SZ + 1) * 4);
  int2* esw0  = (int2*)carve((size_t)E0_SZ * 8);
  int2* esw1  = (int2*)carve((size_t)E1_SZ * 8);
  int*  bsums = (int*)carve(160 * 4);
  (void)ws_size; (void)in_sizes; (void)n_in; (void)out_size;

  hipMemsetAsync(cnt_all, 0, (size_t)(N1_SZ + N2_SZ) * 2 * 4, stream);

  prepw_all_k<<<384, 256, 0, stream>>>(Q0w, W0w, Q1w, W1w, Q0T, W0T, Q1T, W1T);

  // merged CSR build (both layers)
  hist_all_k<<<(E0_SZ + E1_SZ) / 256, 256, 0, stream>>>(dst0, dst1, counts);
  scan_bsums_k<<<(N1_SZ + N2_SZ) / 1024, 256, 0, stream>>>(counts, bsums);
  scan_top2_k<<<2, 256, 0, stream>>>(bsums, offs0 + N1_SZ, offs1 + N2_SZ);
  scan_final_k<<<(N1_SZ + N2_SZ) / 1024, 256, 0, stream>>>(counts, bsums, offs0, offs1);
  scatter_all_k<<<(E0_SZ + E1_SZ) / 256, 256, 0, stream>>>(
      src0, dst0, w0, src1, dst1, w1, offs0, offs1, cursor, esw0, esw1);

  // a0[d] = segsum(w * relu(bf16(emb[nids[src]]) @ Q0 + Q0b)) / clip(segsum(w),1)
  qagg_k<0><<<N1_SZ / 64, 256, 0, stream>>>(emb, nullptr, nids, offs0, esw0,
                                            Q0T, Q0b, a0);
  // h1 = rownorm(relu([a0, emb[nids[:N1]]] @ W0 + W0b))
  gemm_k<2, AM_BF16, AM_GATHER, EPI_NORM>
      <<<N1_SZ / 64, 256, 0, stream>>>(a0, emb, nids, W0T, W0b, h1, nullptr);
  // a1[d] = segsum(w * relu(h1[src] @ Q1 + Q1b)) / clip(segsum(w),1)
  qagg_k<1><<<N2_SZ / 64, 256, 0, stream>>>(nullptr, h1, nullptr, offs1, esw1,
                                            Q1T, Q1b, a1);
  // hitem = rownorm(relu([a1, h1[:N2]] @ W1 + W1b)) + emb[nids[:N2]]
  gemm_k<2, AM_BF16, AM_BF16, EPI_NORM_ADDEMB>
      <<<N2_SZ / 64, 256, 0, stream>>>(a1, h1, nids, W1T, W1b, hitem, emb);

  score_k<<<EP_SZ / 4, 256, 0, stream>>>(hitem, bias, nids, pos_src, pos_dst,
                                         neg_src, neg_dst, out);
}

// Round 2
// 981.332 us; speedup vs baseline: 1.2196x; 1.2196x over previous
//
#include <hip/hip_runtime.h>
#include <stdint.h>

#define V_SZ   1000000
#define N0_SZ  1048576
#define N1_SZ  131072
#define N2_SZ  16384
#define E0_SZ  1048576
#define E1_SZ  131072
#define EP_SZ  16384

typedef short bf16x8 __attribute__((ext_vector_type(8)));
typedef float f32x4  __attribute__((ext_vector_type(4)));

__device__ __forceinline__ unsigned short f2bf(float f) {
  union { float f; unsigned u; } v; v.f = f;
  unsigned r = v.u + 0x7FFFu + ((v.u >> 16) & 1u);   // RNE
  return (unsigned short)(r >> 16);
}
__device__ __forceinline__ float bf2f(unsigned short h) {
  union { unsigned u; float f; } v; v.u = ((unsigned)h) << 16;
  return v.f;
}
__device__ __forceinline__ unsigned pack2bf(float a, float b) {
  return ((unsigned)f2bf(b) << 16) | (unsigned)f2bf(a);
}

// ---------- merged weight prep: 4 weights f32 (K x 128) -> bf16 (128 x K) ----------
__global__ __launch_bounds__(256) void prepw_all_k(
    const float* __restrict__ Q0w, const float* __restrict__ W0w,
    const float* __restrict__ Q1w, const float* __restrict__ W1w,
    unsigned short* __restrict__ Q0T, unsigned short* __restrict__ W0T,
    unsigned short* __restrict__ Q1T, unsigned short* __restrict__ W1T) {
  int t = blockIdx.x * 256 + threadIdx.x;   // total 98304
  const float* W; unsigned short* WT; int K; int base;
  if (t < 16384)      { W = Q0w; WT = Q0T; K = 128; base = 0; }
  else if (t < 49152) { W = W0w; WT = W0T; K = 256; base = 16384; }
  else if (t < 65536) { W = Q1w; WT = Q1T; K = 128; base = 49152; }
  else                { W = W1w; WT = W1T; K = 256; base = 65536; }
  int u = t - base;
  int n = u & 127, k = u >> 7;
  WT[(size_t)n * K + k] = f2bf(W[u]);
}

// ---------- merged CSR build (both layers; counts0|counts1 contiguous) ----------
__global__ __launch_bounds__(256) void hist_all_k(const int* __restrict__ dst0,
                                                  const int* __restrict__ dst1,
                                                  int* __restrict__ counts) {
  int e = blockIdx.x * 256 + threadIdx.x;   // E0+E1
  if (e < E0_SZ) atomicAdd(&counts[dst0[e]], 1);
  else if (e < E0_SZ + E1_SZ) atomicAdd(&counts[N1_SZ + dst1[e - E0_SZ]], 1);
}

// per-1024-chunk sums over the combined counts array (144 blocks)
__global__ __launch_bounds__(256) void scan_bsums_k(const int* __restrict__ counts,
                                                    int* __restrict__ bsums) {
  __shared__ int red[256];
  int base = blockIdx.x * 1024, t = threadIdx.x;
  int s = 0;
  #pragma unroll
  for (int i = 0; i < 4; i++) s += counts[base + t * 4 + i];
  red[t] = s;
  __syncthreads();
  for (int st = 128; st > 0; st >>= 1) {
    if (t < st) red[t] += red[t + st];
    __syncthreads();
  }
  if (t == 0) bsums[blockIdx.x] = red[0];
}

// block 0: exclusive-scan bsums[0:128] (layer0); block 1: bsums[128:144] (layer1)
__global__ __launch_bounds__(256) void scan_top2_k(int* __restrict__ bsums,
                                                   int* __restrict__ offs0_last,
                                                   int* __restrict__ offs1_last) {
  __shared__ int lds[256];
  int b = blockIdx.x, t = threadIdx.x;
  int nb = (b == 0) ? 128 : 16;
  int off = (b == 0) ? 0 : 128;
  int v = (t < nb) ? bsums[off + t] : 0;
  lds[t] = v;
  __syncthreads();
  for (int st = 1; st < 256; st <<= 1) {
    int x = (t >= st) ? lds[t - st] : 0;
    __syncthreads();
    lds[t] += x;
    __syncthreads();
  }
  if (t < nb) bsums[off + t] = lds[t] - v;
  if (t == nb - 1) *((b == 0) ? offs0_last : offs1_last) = lds[t];
}

// final: exclusive scan within each 1024 chunk + add per-layer block prefix
__global__ __launch_bounds__(256) void scan_final_k(const int* __restrict__ counts,
                                                    const int* __restrict__ bsums,
                                                    int* __restrict__ offs0,
                                                    int* __restrict__ offs1) {
  __shared__ int tsum[256];
  int b = blockIdx.x, t = threadIdx.x;
  int base = b * 1024;
  int v0 = counts[base + t * 4 + 0], v1 = counts[base + t * 4 + 1];
  int v2 = counts[base + t * 4 + 2], v3 = counts[base + t * 4 + 3];
  int s = v0 + v1 + v2 + v3;
  tsum[t] = s;
  __syncthreads();
  for (int st = 1; st < 256; st <<= 1) {
    int x = (t >= st) ? tsum[t - st] : 0;
    __syncthreads();
    tsum[t] += x;
    __syncthreads();
  }
  int pre = bsums[b] + tsum[t] - s;
  int* op = (b < 128) ? (offs0 + base) : (offs1 + base - N1_SZ);
  op[t * 4 + 0] = pre;
  op[t * 4 + 1] = pre + v0;
  op[t * 4 + 2] = pre + v0 + v1;
  op[t * 4 + 3] = pre + v0 + v1 + v2;
}

// scatter edges into CSR slots; (src,w) packed 8B + dst 4B per slot
__global__ __launch_bounds__(256) void scatter_all_k(
    const int* __restrict__ src0, const int* __restrict__ dst0, const float* __restrict__ w0,
    const int* __restrict__ src1, const int* __restrict__ dst1, const float* __restrict__ w1,
    const int* __restrict__ offs0, const int* __restrict__ offs1,
    int* __restrict__ cursor,                      // cursor0(N1) | cursor1(N2)
    int2* __restrict__ esw0, int* __restrict__ edst0,
    int2* __restrict__ esw1, int* __restrict__ edst1) {
  int e = blockIdx.x * 256 + threadIdx.x;
  if (e < E0_SZ) {
    int d = dst0[e];
    int p = offs0[d] + atomicAdd(&cursor[d], 1);
    esw0[p] = make_int2(src0[e], __float_as_int(w0[e]));
    edst0[p] = d;
  } else if (e < E0_SZ + E1_SZ) {
    int ee = e - E0_SZ;
    int d = dst1[ee];
    int p = offs1[d] + atomicAdd(&cursor[N1_SZ + d], 1);
    esw1[p] = make_int2(src1[ee], __float_as_int(w1[ee]));
    edst1[p] = d;
  }
}

// ---------- fused gather-GEMM (rows x 128, K = 128*KCHUNKS) ----------
#define AM_GATHER 0
#define AM_BF16   1
#define AM_F32DIV 2
#define EPI_BF16        0
#define EPI_NORM        1
#define EPI_NORM_ADDEMB 2

template <int KCHUNKS, int AM0, int AM1, int EPI>
__global__ __launch_bounds__(256) void gemm_k(const void* __restrict__ asrc0,
                                              const void* __restrict__ asrc1,
                                              const int* __restrict__ ids,
                                              const unsigned short* __restrict__ BT,
                                              const float* __restrict__ biasv,
                                              void* __restrict__ outp,
                                              const float* __restrict__ emb,
                                              const float* __restrict__ wsumv) {
  __shared__ unsigned short lA[64][136];
  __shared__ unsigned short lB[128][136];
  const int tid = threadIdx.x;
  const int lane = tid & 63;
  const int wid = tid >> 6;
  const int rowbase = blockIdx.x * 64;
  const int Ktot = KCHUNKS * 128;

  f32x4 acc[8];
  #pragma unroll
  for (int i = 0; i < 8; i++) acc[i] = (f32x4){0.f, 0.f, 0.f, 0.f};

  for (int c = 0; c < KCHUNKS; ++c) {
    if (c) __syncthreads();
    const int am = (c == 0) ? AM0 : AM1;
    const void* asrc = (c == 0) ? asrc0 : asrc1;
    if (am == AM_GATHER) {
      const float* fsrc = (const float*)asrc;
      #pragma unroll
      for (int i = 0; i < 8; i++) {
        int f = i * 256 + tid;
        int r = f >> 5, c4 = f & 31;
        const float* rp = fsrc + (size_t)ids[rowbase + r] * 128;
        float4 v = *(const float4*)(rp + c4 * 4);
        uint2 pk;
        pk.x = pack2bf(v.x, v.y);
        pk.y = pack2bf(v.z, v.w);
        *(uint2*)(&lA[r][c4 * 4]) = pk;
      }
    } else if (am == AM_F32DIV) {
      const float* fsrc = (const float*)asrc;
      #pragma unroll
      for (int i = 0; i < 8; i++) {
        int f = i * 256 + tid;
        int r = f >> 5, c4 = f & 31;
        int row = rowbase + r;
        float inv = 1.0f / fmaxf(wsumv[row], 1.0f);
        const float* rp = fsrc + (size_t)row * 128;
        float4 v = *(const float4*)(rp + c4 * 4);
        uint2 pk;
        pk.x = pack2bf(v.x * inv, v.y * inv);
        pk.y = pack2bf(v.z * inv, v.w * inv);
        *(uint2*)(&lA[r][c4 * 4]) = pk;
      }
    } else {
      const unsigned short* bsrc = (const unsigned short*)asrc;
      #pragma unroll
      for (int i = 0; i < 4; i++) {
        int f = i * 256 + tid;
        int r = f >> 4, c8 = f & 15;
        uint4 v = *(const uint4*)(bsrc + (size_t)(rowbase + r) * 128 + c8 * 8);
        *(uint4*)(&lA[r][c8 * 8]) = v;
      }
    }
    {
      const unsigned short* bp = BT + c * 128;
      #pragma unroll
      for (int i = 0; i < 8; i++) {
        int f = i * 256 + tid;
        int n = f >> 4, c8 = f & 15;
        uint4 v = *(const uint4*)(bp + (size_t)n * Ktot + c8 * 8);
        *(uint4*)(&lB[n][c8 * 8]) = v;
      }
    }
    __syncthreads();

    const int mr = wid * 16 + (lane & 15);
    const int kq = (lane >> 4) * 8;
    #pragma unroll
    for (int kk = 0; kk < 128; kk += 32) {
      bf16x8 af = *(const bf16x8*)(&lA[mr][kk + kq]);
      #pragma unroll
      for (int nt = 0; nt < 8; ++nt) {
        bf16x8 bfr = *(const bf16x8*)(&lB[nt * 16 + (lane & 15)][kk + kq]);
        acc[nt] = __builtin_amdgcn_mfma_f32_16x16x32_bf16(af, bfr, acc[nt], 0, 0, 0);
      }
    }
  }

  // epilogue: C/D layout col=lane&15 (+16*nt), row=(lane>>4)*4+r
  const int crow = wid * 16 + ((lane >> 4) << 2);
  float vreg[8][4];
  #pragma unroll
  for (int nt = 0; nt < 8; ++nt) {
    int col = nt * 16 + (lane & 15);
    float b = biasv[col];
    #pragma unroll
    for (int r = 0; r < 4; ++r) {
      float v = acc[nt][r] + b;
      vreg[nt][r] = v > 0.f ? v : 0.f;
    }
  }
  if (EPI == EPI_BF16) {
    unsigned short* op = (unsigned short*)outp;
    #pragma unroll
    for (int nt = 0; nt < 8; ++nt) {
      int col = nt * 16 + (lane & 15);
      #pragma unroll
      for (int r = 0; r < 4; ++r)
        op[(size_t)(rowbase + crow + r) * 128 + col] = f2bf(vreg[nt][r]);
    }
  } else {
    float ss[4] = {0.f, 0.f, 0.f, 0.f};
    #pragma unroll
    for (int nt = 0; nt < 8; ++nt)
      #pragma unroll
      for (int r = 0; r < 4; ++r) ss[r] += vreg[nt][r] * vreg[nt][r];
    #pragma unroll
    for (int r = 0; r < 4; ++r) {
      ss[r] += __shfl_xor(ss[r], 1);
      ss[r] += __shfl_xor(ss[r], 2);
      ss[r] += __shfl_xor(ss[r], 4);
      ss[r] += __shfl_xor(ss[r], 8);
    }
    float sc[4];
    #pragma unroll
    for (int r = 0; r < 4; ++r) sc[r] = ss[r] > 0.f ? rsqrtf(ss[r]) : 1.0f;
    if (EPI == EPI_NORM) {
      unsigned short* op = (unsigned short*)outp;
      #pragma unroll
      for (int nt = 0; nt < 8; ++nt) {
        int col = nt * 16 + (lane & 15);
        #pragma unroll
        for (int r = 0; r < 4; ++r)
          op[(size_t)(rowbase + crow + r) * 128 + col] = f2bf(vreg[nt][r] * sc[r]);
      }
    } else {
      float* op = (float*)outp;
      #pragma unroll
      for (int nt = 0; nt < 8; ++nt) {
        int col = nt * 16 + (lane & 15);
        #pragma unroll
        for (int r = 0; r < 4; ++r) {
          int row = rowbase + crow + r;
          op[(size_t)row * 128 + col] =
              vreg[nt][r] * sc[r] + emb[(size_t)ids[row] * 128 + col];
        }
      }
    }
  }
}

// ---------- per-edge-chunk Q-GEMM + segmented reduce into f32 accumulators ----------
// Grid = E/64 blocks (max parallelism). Block handles 64 CSR-consecutive edge
// slots: gather A rows -> ONE barrier -> GEMM (each wave's A rows are its own
// 16) -> relu'd rows back to own LDS rows -> run-length segment reduce over the
// wave's 16 rows (dsts sorted within CSR) -> flush: plain store if the dst run
// is exclusively owned (checked vs neighbor dsts), else atomicAdd f32.
template <int LAYER>   // 0: A row = emb[nids[src]] (f32); 1: A row = hsrc[src] (bf16)
__global__ __launch_bounds__(256) void eqagg_k(
    const float* __restrict__ embf,
    const unsigned short* __restrict__ hsrc,
    const int* __restrict__ nids,
    const int2* __restrict__ esw,          // (src, w-bits) per CSR slot
    const int* __restrict__ edst,          // dst per CSR slot
    const unsigned short* __restrict__ BT, // 128x128 bf16, n-major
    const float* __restrict__ biasv,
    float* __restrict__ aoutf,             // [ndst][128] f32, zero-init
    float* __restrict__ wsumf) {           // [ndst] f32, zero-init
  constexpr int ETOT = (LAYER == 0) ? E0_SZ : E1_SZ;
  __shared__ unsigned short lA[64][136];
  __shared__ unsigned short lB[128][136];
  __shared__ float lw[64];
  __shared__ int ldst[64];
  const int tid = threadIdx.x;
  const int lane = tid & 63;
  const int wid = tid >> 6;
  const int base0 = blockIdx.x * 64;

  // stage B (32KB, L2-resident weight)
  #pragma unroll
  for (int i = 0; i < 8; i++) {
    int f = i * 256 + tid;
    int n = f >> 4, c8 = f & 15;
    *(uint4*)(&lB[n][c8 * 8]) = *(const uint4*)(BT + (size_t)n * 128 + c8 * 8);
  }
  if (tid < 64) {
    int2 sw = esw[base0 + tid];
    lw[tid] = __int_as_float(sw.y);
    ldst[tid] = edst[base0 + tid];
  }
  // stage gathered A rows
  if (LAYER == 0) {
    #pragma unroll
    for (int i = 0; i < 8; i++) {
      int f = i * 256 + tid;
      int r = f >> 5, c4 = f & 31;
      int s = esw[base0 + r].x;
      const float* rp = embf + (size_t)nids[s] * 128;
      float4 v = *(const float4*)(rp + c4 * 4);
      uint2 pk;
      pk.x = pack2bf(v.x, v.y);
      pk.y = pack2bf(v.z, v.w);
      *(uint2*)(&lA[r][c4 * 4]) = pk;
    }
  } else {
    #pragma unroll
    for (int i = 0; i < 4; i++) {
      int f = i * 256 + tid;
      int r = f >> 4, c8 = f & 15;
      int s = esw[base0 + r].x;
      *(uint4*)(&lA[r][c8 * 8]) = *(const uint4*)(hsrc + (size_t)s * 128 + c8 * 8);
    }
  }
  __syncthreads();   // the only barrier

  // GEMM: wave wid computes rows [wid*16, wid*16+16) (its own lA rows)
  const int mr = wid * 16 + (lane & 15);
  const int kq = (lane >> 4) * 8;
  f32x4 acc[8];
  #pragma unroll
  for (int i = 0; i < 8; i++) acc[i] = (f32x4){0.f, 0.f, 0.f, 0.f};
  #pragma unroll
  for (int kk = 0; kk < 128; kk += 32) {
    bf16x8 af = *(const bf16x8*)(&lA[mr][kk + kq]);
    #pragma unroll
    for (int nt = 0; nt < 8; ++nt) {
      bf16x8 bfr = *(const bf16x8*)(&lB[nt * 16 + (lane & 15)][kk + kq]);
      acc[nt] = __builtin_amdgcn_mfma_f32_16x16x32_bf16(af, bfr, acc[nt], 0, 0, 0);
    }
  }
  // relu(+bias) -> write back into this wave's own 16 lA rows (no barrier:
  // no other wave ever reads them)
  const int crow = wid * 16 + ((lane >> 4) << 2);
  #pragma unroll
  for (int nt = 0; nt < 8; ++nt) {
    int col = nt * 16 + (lane & 15);
    float b = biasv[col];
    #pragma unroll
    for (int r = 0; r < 4; ++r) {
      float v = acc[nt][r] + b;
      lA[crow + r][col] = f2bf(v > 0.f ? v : 0.f);
    }
  }

  // segmented reduce over this wave's 16 rows; lane covers 2 columns
  const int r0 = wid * 16;
  const int prevd = (wid > 0) ? ldst[r0 - 1]
                              : (base0 > 0 ? edst[base0 - 1] : -1);
  const int nextd = (wid < 3) ? ldst[r0 + 16]
                              : (base0 + 64 < ETOT ? edst[base0 + 64] : -1);
  float ax = 0.f, ay = 0.f, wa = 0.f;
  int cur = ldst[r0];
  int rstart = 0;
  #pragma unroll
  for (int rr = 0; rr < 16; ++rr) {
    int d = ldst[r0 + rr];
    if (d != cur) {   // wave-uniform branch
      bool interior = (rstart > 0 || prevd != cur);   // run ended before rr<16
      float* rowp = aoutf + (size_t)cur * 128 + lane * 2;
      if (interior) {
        rowp[0] = ax; rowp[1] = ay;
        if (lane == 0) wsumf[cur] = wa;
      } else {
        atomicAdd(rowp, ax); atomicAdd(rowp + 1, ay);
        if (lane == 0) atomicAdd(&wsumf[cur], wa);
      }
      ax = ay = wa = 0.f;
      cur = d;
      rstart = rr;
    }
    float w = lw[r0 + rr];
    unsigned u = *(const unsigned*)(&lA[r0 + rr][lane * 2]);
    ax += w * bf2f((unsigned short)(u & 0xffffu));
    ay += w * bf2f((unsigned short)(u >> 16));
    wa += w;
  }
  {
    bool interior = (rstart > 0 || prevd != cur) && (nextd != cur);
    float* rowp = aoutf + (size_t)cur * 128 + lane * 2;
    if (interior) {
      rowp[0] = ax; rowp[1] = ay;
      if (lane == 0) wsumf[cur] = wa;
    } else {
      atomicAdd(rowp, ax); atomicAdd(rowp + 1, ay);
      if (lane == 0) atomicAdd(&wsumf[cur], wa);
    }
  }
}

// ---------- final scores (bias gathered inline through nids) ----------
__global__ __launch_bounds__(256) void score_k(const float* __restrict__ hitem,
                                               const float* __restrict__ bias,
                                               const int* __restrict__ nids,
                                               const int* __restrict__ ps,
                                               const int* __restrict__ pd,
                                               const int* __restrict__ ns,
                                               const int* __restrict__ nd,
                                               float* __restrict__ out) {
  int wid = threadIdx.x >> 6, lane = threadIdx.x & 63;
  int e = blockIdx.x * 4 + wid;
  if (e >= EP_SZ) return;
  int a = ps[e], b = pd[e], c = ns[e], d = nd[e];
  float2 va = ((const float2*)(hitem + (size_t)a * 128))[lane];
  float2 vb = ((const float2*)(hitem + (size_t)b * 128))[lane];
  float2 vc = ((const float2*)(hitem + (size_t)c * 128))[lane];
  float2 vd = ((const float2*)(hitem + (size_t)d * 128))[lane];
  float dp = va.x * vb.x + va.y * vb.y;
  float dn = vc.x * vd.x + vc.y * vd.y;
  #pragma unroll
  for (int m = 1; m < 64; m <<= 1) {
    dp += __shfl_xor(dp, m);
    dn += __shfl_xor(dn, m);
  }
  if (lane == 0) {
    float sp = dp + bias[nids[a]] + bias[nids[b]];
    float sn = dn + bias[nids[c]] + bias[nids[d]];
    out[e] = fmaxf(sn - sp + 1.0f, 0.0f);
  }
}

extern "C" void kernel_launch(void* const* d_in, const int* in_sizes, int n_in,
                              void* d_out, int out_size, void* d_ws, size_t ws_size,
                              hipStream_t stream) {
  const float* emb  = (const float*)d_in[0];
  const float* bias = (const float*)d_in[1];
  const int* nids   = (const int*)d_in[2];
  const int* src0   = (const int*)d_in[3];
  const int* dst0   = (const int*)d_in[4];
  const float* w0   = (const float*)d_in[5];
  const int* src1   = (const int*)d_in[6];
  const int* dst1   = (const int*)d_in[7];
  const float* w1   = (const float*)d_in[8];
  const int* pos_src = (const int*)d_in[9];
  const int* pos_dst = (const int*)d_in[10];
  const int* neg_src = (const int*)d_in[11];
  const int* neg_dst = (const int*)d_in[12];
  const float* Q0w = (const float*)d_in[13];
  const float* Q0b = (const float*)d_in[14];
  const float* W0w = (const float*)d_in[15];
  const float* W0b = (const float*)d_in[16];
  const float* Q1w = (const float*)d_in[17];
  const float* Q1b = (const float*)d_in[18];
  const float* W1w = (const float*)d_in[19];
  const float* W1b = (const float*)d_in[20];
  float* out = (float*)d_out;

  char* ws = (char*)d_ws;
  size_t p = 0;
  auto carve = [&](size_t sz) { void* r = ws + p; p = (p + sz + 255) & ~(size_t)255; return r; };

  // ---- zero-init region (contiguous): a0f | wsum0 | a1f | wsum1 | cnt_all ----
  float* a0f   = (float*)carve((size_t)N1_SZ * 128 * 4);
  float* wsum0 = (float*)carve((size_t)N1_SZ * 4);
  float* a1f   = (float*)carve((size_t)N2_SZ * 128 * 4);
  float* wsum1 = (float*)carve((size_t)N2_SZ * 4);
  int* cnt_all = (int*)carve((size_t)(N1_SZ + N2_SZ) * 2 * 4);
  size_t zlen  = p;   // from ws start
  int* counts  = cnt_all;
  int* cursor  = cnt_all + (N1_SZ + N2_SZ);
  // ---- rest ----
  unsigned short* h1    = (unsigned short*)carve((size_t)N1_SZ * 128 * 2);
  float*          hitem = (float*)carve((size_t)N2_SZ * 128 * 4);
  unsigned short* Q0T = (unsigned short*)carve(128 * 128 * 2);
  unsigned short* W0T = (unsigned short*)carve(256 * 128 * 2);
  unsigned short* Q1T = (unsigned short*)carve(128 * 128 * 2);
  unsigned short* W1T = (unsigned short*)carve(256 * 128 * 2);
  int*  offs0 = (int*)carve((N1_SZ + 1) * 4);
  int*  offs1 = (int*)carve((N2_SZ + 1) * 4);
  int2* esw0  = (int2*)carve((size_t)E0_SZ * 8);
  int*  edst0 = (int*)carve((size_t)E0_SZ * 4);
  int2* esw1  = (int2*)carve((size_t)E1_SZ * 8);
  int*  edst1 = (int*)carve((size_t)E1_SZ * 4);
  int*  bsums = (int*)carve(160 * 4);
  (void)ws_size; (void)in_sizes; (void)n_in; (void)out_size;

  hipMemsetAsync(ws, 0, zlen, stream);

  prepw_all_k<<<384, 256, 0, stream>>>(Q0w, W0w, Q1w, W1w, Q0T, W0T, Q1T, W1T);

  // merged CSR build (both layers)
  hist_all_k<<<(E0_SZ + E1_SZ) / 256, 256, 0, stream>>>(dst0, dst1, counts);
  scan_bsums_k<<<(N1_SZ + N2_SZ) / 1024, 256, 0, stream>>>(counts, bsums);
  scan_top2_k<<<2, 256, 0, stream>>>(bsums, offs0 + N1_SZ, offs1 + N2_SZ);
  scan_final_k<<<(N1_SZ + N2_SZ) / 1024, 256, 0, stream>>>(counts, bsums, offs0, offs1);
  scatter_all_k<<<(E0_SZ + E1_SZ) / 256, 256, 0, stream>>>(
      src0, dst0, w0, src1, dst1, w1, offs0, offs1, cursor,
      esw0, edst0, esw1, edst1);

  // a0f/wsum0 += per-edge relu(bf16(emb[nids[src]]) @ Q0 + Q0b) * w  (segmented)
  eqagg_k<0><<<E0_SZ / 64, 256, 0, stream>>>(emb, nullptr, nids, esw0, edst0,
                                             Q0T, Q0b, a0f, wsum0);
  // h1 = rownorm(relu([a0f/clip(wsum0,1), emb[nids[:N1]]] @ W0 + W0b))
  gemm_k<2, AM_F32DIV, AM_GATHER, EPI_NORM>
      <<<N1_SZ / 64, 256, 0, stream>>>(a0f, emb, nids, W0T, W0b, h1, nullptr, wsum0);
  // a1f/wsum1 += per-edge relu(h1[src] @ Q1 + Q1b) * w  (segmented)
  eqagg_k<1><<<E1_SZ / 64, 256, 0, stream>>>(nullptr, h1, nullptr, esw1, edst1,
                                             Q1T, Q1b, a1f, wsum1);
  // hitem = rownorm(relu([a1f/clip(wsum1,1), h1[:N2]] @ W1 + W1b)) + emb[nids[:N2]]
  gemm_k<2, AM_F32DIV, AM_BF16, EPI_NORM_ADDEMB>
      <<<N2_SZ / 64, 256, 0, stream>>>(a1f, h1, nids, W1T, W1b, hitem, emb, wsum1);

  score_k<<<EP_SZ / 4, 256, 0, stream>>>(hitem, bias, nids, pos_src, pos_dst,
                                         neg_src, neg_dst, out);
}